// Round 1
// baseline (47709.402 us; speedup 1.0000x reference)
//
#include <hip/hip_runtime.h>
#include <math.h>

// Problem constants (Discriminator: bidirectional 2-layer GRU + FC head)
#define BB 64    // batch
#define TT 1024  // seq len
#define DD 128   // input dim
#define HH 512   // hidden dim

// ---------------------------------------------------------------------------
// Workspace layout (floats):
//   h0   : [2 dir][2 parity][BB][HH]   = 131072 floats
//   h1   : [2 dir][2 parity][BB][HH]   = 131072
//   fc_in: [BB][2048]                  = 131072
//   fc1o : [BB][1024]                  =  65536
//   fc2o : [BB][512]                   =  32768
// total ~1.9 MB
// ---------------------------------------------------------------------------

struct GruParams {
  const float* x;
  const float* Wih[4];  // [dir*2 + layer]
  const float* Whh[4];
  const float* bih[4];
  const float* bhh[4];
  float* h0;            // [2][2][BB][HH]
  float* h1;            // [2][2][BB][HH]
  int s;                // pipeline step: L0 computes t=s, L1 computes t=s-1
};

// One pipeline step. Grid = 512 blocks x 256 threads.
//   unit = bid>>7 : 0 = fwd-L0, 1 = bwd-L0, 2 = fwd-L1, 3 = bwd-L1
//   wg   = bid&127: jslice = wg&63 (8 hidden dims), bhalf = wg>>6 (32 rows)
// Parity: read (s+1)&1, write s&1. Kernel boundary is the global barrier.
__global__ __launch_bounds__(256) void gru_step_k(GruParams p) {
  const int bid   = blockIdx.x;
  const int unit  = bid >> 7;
  const int layer = unit >> 1;
  const int dir   = unit & 1;
  const int s     = p.s;
  if (layer == 0 && s >= TT) return;  // L0 idle at s == TT
  if (layer == 1 && s == 0)  return;  // L1 idle at s == 0
  const int t      = (layer == 0) ? s : (s - 1);
  const int wg     = bid & 127;
  const int jslice = wg & 63;
  const int bhalf  = wg >> 6;
  const int j0     = jslice * 8;
  const int pw     = s & 1;
  const int pr     = pw ^ 1;

  const int u = dir * 2 + layer;
  const float* __restrict__ Wih = p.Wih[u];
  const float* __restrict__ Whh = p.Whh[u];
  const float* __restrict__ bih = p.bih[u];
  const float* __restrict__ bhh = p.bhh[u];
  float* hbuf = (layer == 0) ? p.h0 : p.h1;
  const float* __restrict__ hprev = hbuf + (size_t)(dir * 2 + pr) * BB * HH;
  float*       __restrict__ hnew  = hbuf + (size_t)(dir * 2 + pw) * BB * HH;

  const int tid = threadIdx.x;
  const int bl  = tid & 31;        // local batch row
  const int b   = bhalf * 32 + bl; // global batch row
  const int jg  = tid >> 5;        // 0..7
  const int j   = j0 + jg;         // hidden dim owned by this thread

  // input-vector tile, stored transposed [k][b] for conflict-free reads
  __shared__ float iv[64][33];

  float acc_i0 = 0.f, acc_i1 = 0.f, acc_i2 = 0.f;
  float acc_h0 = 0.f, acc_h1 = 0.f, acc_h2 = 0.f;

  // stager mapping: each thread loads 8 consecutive k for one batch row
  const int sr = tid >> 3;        // 0..31 local row
  const int sc = (tid & 7) * 8;   // 0..56 k offset

  // ---------------- phase A: input contribution (gi) ----------------
  const float* isrc;
  size_t istride;
  int Kin;
  if (layer == 0) {
    const int tx = (dir == 0) ? t : (TT - 1 - t);
    isrc    = p.x + (size_t)tx * DD;
    istride = (size_t)TT * DD;
    Kin     = DD;
  } else {
    // layer-1 input is layer-0's output at time t (written last launch)
    isrc    = p.h0 + (size_t)(dir * 2 + pr) * BB * HH;
    istride = HH;
    Kin     = HH;
  }
  for (int k0 = 0; k0 < Kin; k0 += 64) {
    __syncthreads();
    {
      const float* src = isrc + (size_t)(bhalf * 32 + sr) * istride + k0 + sc;
      #pragma unroll
      for (int i = 0; i < 8; ++i) iv[sc + i][sr] = src[i];
    }
    __syncthreads();
    const float* w0 = Wih + (size_t)(0 * HH + j) * Kin + k0;
    const float* w1 = Wih + (size_t)(1 * HH + j) * Kin + k0;
    const float* w2 = Wih + (size_t)(2 * HH + j) * Kin + k0;
    #pragma unroll 4
    for (int kk = 0; kk < 64; kk += 4) {
      const float4 wa = *(const float4*)(w0 + kk);
      const float4 wb = *(const float4*)(w1 + kk);
      const float4 wc = *(const float4*)(w2 + kk);
      const float x0 = iv[kk + 0][bl];
      const float x1 = iv[kk + 1][bl];
      const float x2 = iv[kk + 2][bl];
      const float x3 = iv[kk + 3][bl];
      acc_i0 += wa.x * x0 + wa.y * x1 + wa.z * x2 + wa.w * x3;
      acc_i1 += wb.x * x0 + wb.y * x1 + wb.z * x2 + wb.w * x3;
      acc_i2 += wc.x * x0 + wc.y * x1 + wc.z * x2 + wc.w * x3;
    }
  }

  // ---------------- phase B: hidden contribution (gh) ----------------
  for (int k0 = 0; k0 < HH; k0 += 64) {
    __syncthreads();
    {
      const float* src = hprev + (size_t)(bhalf * 32 + sr) * HH + k0 + sc;
      #pragma unroll
      for (int i = 0; i < 8; ++i) iv[sc + i][sr] = src[i];
    }
    __syncthreads();
    const float* w0 = Whh + (size_t)(0 * HH + j) * HH + k0;
    const float* w1 = Whh + (size_t)(1 * HH + j) * HH + k0;
    const float* w2 = Whh + (size_t)(2 * HH + j) * HH + k0;
    #pragma unroll 4
    for (int kk = 0; kk < 64; kk += 4) {
      const float4 wa = *(const float4*)(w0 + kk);
      const float4 wb = *(const float4*)(w1 + kk);
      const float4 wc = *(const float4*)(w2 + kk);
      const float x0 = iv[kk + 0][bl];
      const float x1 = iv[kk + 1][bl];
      const float x2 = iv[kk + 2][bl];
      const float x3 = iv[kk + 3][bl];
      acc_h0 += wa.x * x0 + wa.y * x1 + wa.z * x2 + wa.w * x3;
      acc_h1 += wb.x * x0 + wb.y * x1 + wb.z * x2 + wb.w * x3;
      acc_h2 += wc.x * x0 + wc.y * x1 + wc.z * x2 + wc.w * x3;
    }
  }

  // ---------------- gates ----------------
  const float gir = acc_i0 + bih[j];
  const float giz = acc_i1 + bih[HH + j];
  const float gin = acc_i2 + bih[2 * HH + j];
  const float ghr = acc_h0 + bhh[j];
  const float ghz = acc_h1 + bhh[HH + j];
  const float ghn = acc_h2 + bhh[2 * HH + j];
  const float r = 1.f / (1.f + expf(-(gir + ghr)));
  const float z = 1.f / (1.f + expf(-(giz + ghz)));
  const float n = tanhf(gin + r * ghn);
  const float hold = hprev[(size_t)b * HH + j];
  hnew[(size_t)b * HH + j] = (1.f - z) * n + z * hold;
}

__global__ void zero_k(float* p, int nelem) {
  const int i = blockIdx.x * blockDim.x + threadIdx.x;
  if (i < nelem) p[i] = 0.f;
}

// hidden = [h0_f | h1_f | h0_b | h1_b]; h0 final parity 1, h1 final parity 0
__global__ void gather_hidden_k(const float* __restrict__ h0,
                                const float* __restrict__ h1,
                                float* __restrict__ fc_in) {
  const int idx = blockIdx.x * blockDim.x + threadIdx.x;  // 64*2048
  const int b  = idx >> 11;
  const int c  = idx & 2047;
  const int seg = c >> 9;   // 0:f-L0 1:f-L1 2:b-L0 3:b-L1
  const int cc  = c & 511;
  float v;
  if      (seg == 0) v = h0[(size_t)(0 * 2 + 1) * BB * HH + b * HH + cc];
  else if (seg == 1) v = h1[(size_t)(0 * 2 + 0) * BB * HH + b * HH + cc];
  else if (seg == 2) v = h0[(size_t)(1 * 2 + 1) * BB * HH + b * HH + cc];
  else               v = h1[(size_t)(1 * 2 + 0) * BB * HH + b * HH + cc];
  fc_in[idx] = v;
}

// out[b][n] = act(dot(in[b,:], W[n,:]) + bias[n]); one thread per output
__global__ void fc_k(const float* __restrict__ in, const float* __restrict__ W,
                     const float* __restrict__ bias, float* __restrict__ out,
                     int K, int N, int leaky) {
  const int idx = blockIdx.x * blockDim.x + threadIdx.x;
  const int b = idx / N;
  const int n = idx - b * N;
  if (b >= BB) return;
  const float* ir = in + (size_t)b * K;
  const float* wr = W + (size_t)n * K;
  float acc = 0.f;
  for (int k = 0; k < K; k += 4) {
    const float4 a = *(const float4*)(ir + k);
    const float4 w = *(const float4*)(wr + k);
    acc += a.x * w.x + a.y * w.y + a.z * w.z + a.w * w.w;
  }
  acc += bias[n];
  if (leaky) acc = acc > 0.f ? acc : 0.01f * acc;
  out[idx] = acc;
}

extern "C" void kernel_launch(void* const* d_in, const int* in_sizes, int n_in,
                              void* d_out, int out_size, void* d_ws, size_t ws_size,
                              hipStream_t stream) {
  (void)in_sizes; (void)n_in; (void)out_size; (void)ws_size;

  GruParams P;
  P.x = (const float*)d_in[0];
  // input order: x, then for dir in (f,b): for l in (0,1): Wih, Whh, bih, bhh
  for (int dir = 0; dir < 2; ++dir) {
    for (int l = 0; l < 2; ++l) {
      const int base = 1 + (dir * 2 + l) * 4;
      const int u = dir * 2 + l;
      P.Wih[u] = (const float*)d_in[base + 0];
      P.Whh[u] = (const float*)d_in[base + 1];
      P.bih[u] = (const float*)d_in[base + 2];
      P.bhh[u] = (const float*)d_in[base + 3];
    }
  }
  const float* Wfc0 = (const float*)d_in[17];
  const float* bfc0 = (const float*)d_in[18];
  const float* Wfc1 = (const float*)d_in[19];
  const float* bfc1 = (const float*)d_in[20];
  const float* Wfc2 = (const float*)d_in[21];
  const float* bfc2 = (const float*)d_in[22];

  float* ws    = (float*)d_ws;
  float* h0    = ws;                 // 131072
  float* h1    = ws + 131072;       // 131072
  float* fc_in = ws + 262144;       // 131072
  float* fc1o  = ws + 393216;       //  65536
  float* fc2o  = ws + 458752;       //  32768
  P.h0 = h0;
  P.h1 = h1;

  // zero both parities of h0/h1 (read before first write; graph-replay safe)
  hipLaunchKernelGGL(zero_k, dim3(1024), dim3(256), 0, stream, h0, 262144);

  // pipelined recurrence: launch s runs L0 step s and L1 step s-1
  for (int s = 0; s <= TT; ++s) {
    P.s = s;
    hipLaunchKernelGGL(gru_step_k, dim3(512), dim3(256), 0, stream, P);
  }

  // FC head
  hipLaunchKernelGGL(gather_hidden_k, dim3(512), dim3(256), 0, stream, h0, h1, fc_in);
  hipLaunchKernelGGL(fc_k, dim3(256), dim3(256), 0, stream, fc_in, Wfc0, bfc0, fc1o, 2048, 1024, 1);
  hipLaunchKernelGGL(fc_k, dim3(128), dim3(256), 0, stream, fc1o, Wfc1, bfc1, fc2o, 1024, 512, 1);
  hipLaunchKernelGGL(fc_k, dim3(1),   dim3(256), 0, stream, fc2o, Wfc2, bfc2, (float*)d_out, 512, 1, 0);
}